// Round 1
// baseline (1284.731 us; speedup 1.0000x reference)
//
#include <hip/hip_runtime.h>

// out[index[i]] += value[i], duplicates accumulate (aten.index_put accumulate=True).
// N = 16,777,216 (table), M = 33,554,432 (updates). All int32 on device
// (JAX default x64-disabled downcasts int64 -> int32; harness passes int*).

__global__ void ip_copy_kernel(const int4* __restrict__ in, int4* __restrict__ out, int n4) {
    int stride = gridDim.x * blockDim.x;
    for (int i = blockIdx.x * blockDim.x + threadIdx.x; i < n4; i += stride) {
        out[i] = in[i];
    }
}

__global__ void ip_scatter_kernel(const int4* __restrict__ index, const int4* __restrict__ value,
                                  int* __restrict__ out, int m4) {
    int stride = gridDim.x * blockDim.x;
    for (int i = blockIdx.x * blockDim.x + threadIdx.x; i < m4; i += stride) {
        int4 id = index[i];
        int4 v  = value[i];
        atomicAdd(&out[id.x], v.x);
        atomicAdd(&out[id.y], v.y);
        atomicAdd(&out[id.z], v.z);
        atomicAdd(&out[id.w], v.w);
    }
}

extern "C" void kernel_launch(void* const* d_in, const int* in_sizes, int n_in,
                              void* d_out, int out_size, void* d_ws, size_t ws_size,
                              hipStream_t stream) {
    const int* input = (const int*)d_in[0];
    const int* index = (const int*)d_in[1];
    const int* value = (const int*)d_in[2];
    int* out = (int*)d_out;

    const int N = in_sizes[0];   // 16,777,216
    const int M = in_sizes[1];   // 33,554,432

    const int n4 = N / 4;
    const int m4 = M / 4;

    const int block = 256;
    // Memory-bound: cap grid ~2048 blocks, grid-stride the rest (G11).
    const int grid_copy    = 2048;
    const int grid_scatter = 2048;

    ip_copy_kernel<<<grid_copy, block, 0, stream>>>(
        (const int4*)input, (int4*)d_out, n4);
    ip_scatter_kernel<<<grid_scatter, block, 0, stream>>>(
        (const int4*)index, (const int4*)value, out, m4);
}